// Round 8
// baseline (138.889 us; speedup 1.0000x reference)
//
#include <hip/hip_runtime.h>

// Soft histogram, fully fused single dispatch:
//   hist[b,c,j] = (1/P) * sum_pixels f_j(x),  f_j(x) = k_j(x)/(sum_j k_j(x)+1e-12)
// Each block histograms its 8192-pixel chunk into 1024 quant cells (LDS),
// contracts them on the fly against a BANDED Gaussian kernel (sigma*NQ~20
// cells -> only ~+-8 bins significant; truncation <= e^-20), and hands a
// 64-float partial to the last-block finalizer per image.
//
// R2:  two dispatches, disjoint partials.                     90.0 us
// R3/4: 1024-thread finalize -> container died twice. Banned.
// R5:  wide-unroll 256-thr finalize.                          75.7 us
// R6:  8-way split + __threadfence (L2 maintenance x192).     86.9 us
// R7:  fence-free atomic split.                               74.0 us
// R8:  fused; 77.5 us kernel, all pipes idle. Blamed hot-line RMWs.
// R9:  contention-free handoff: IDENTICAL 77.5 us -> RMWs were never it.
//      Smoking gun in counters: VGPR_Count=20 with float4 v[8] + float e[16]
//      declared => compiler SPILLED both arrays to scratch. ~128 scratch
//      dwords/thread x 196K threads ~ 100 MB hidden L2 traffic + per-element
//      vmcnt stalls = the 60 us. (Explains VALU 5%, HBM 2%, no counter.)
// R10: allocation-free phase 2: recompute exp (VALU is 95% idle) in two
//      passes instead of storing e[16]; __launch_bounds__(256,2) for an
//      explicit 256-VGPR budget. Bit-identical band math. Handoff kept
//      from R9 (disjoint atomicExch slots, padded monotonic tickets).

#define NQ      1024
#define NBINS   64
#define NIMG    24            // B*C = 8*3
#define IMG_PIX (512 * 512)   // 262144 pixels per (b,c) image
#define BPI     32            // count blocks per image
#define CNT_BLOCKS (NIMG * BPI)        // 768
#define BANDW   16            // banded kernel window (covers jc-7..jc+8)

__device__ float        g_part[CNT_BLOCKS * NBINS];  // disjoint per-block slots
__device__ unsigned int g_ticket[NIMG * 32];         // 128B stride, monotonic

__global__ __launch_bounds__(256, 2) void soft_hist_fused(
    const float* __restrict__ x, const float* __restrict__ centers,
    float* __restrict__ out)
{
    __shared__ unsigned int h[NQ];
    __shared__ float        fh[NBINS];    // block's contracted 64-bin partial
    __shared__ float        cl[NBINS];    // centers
    __shared__ float        red[4][NBINS];
    __shared__ unsigned int s_last;

    const int bid = blockIdx.x;
    const int t   = threadIdx.x;
    const int img = bid >> 5;             // bid / BPI

    #pragma unroll
    for (int k = 0; k < NQ / 256; ++k) h[t + k * 256] = 0u;
    if (t < NBINS) { fh[t] = 0.0f; cl[t] = centers[t]; }
    __syncthreads();

    // ---- phase 1: histogram 8192 pixels (contiguous 32 KB chunk) ----
    const float4* x4 = (const float4*)x + (size_t)bid * (IMG_PIX / 4 / BPI);
    float4 v[8];
    #pragma unroll
    for (int r = 0; r < 8; ++r) v[r] = x4[r * 256 + t];

    #pragma unroll
    for (int r = 0; r < 8; ++r) {
        const float4 p = v[r];
        int q0 = (int)(p.x * (float)NQ); q0 = q0 < 0 ? 0 : (q0 > NQ - 1 ? NQ - 1 : q0);
        int q1 = (int)(p.y * (float)NQ); q1 = q1 < 0 ? 0 : (q1 > NQ - 1 ? NQ - 1 : q1);
        int q2 = (int)(p.z * (float)NQ); q2 = q2 < 0 ? 0 : (q2 > NQ - 1 ? NQ - 1 : q2);
        int q3 = (int)(p.w * (float)NQ); q3 = q3 < 0 ? 0 : (q3 > NQ - 1 ? NQ - 1 : q3);
        atomicAdd(&h[q0], 1u);
        atomicAdd(&h[q1], 1u);
        atomicAdd(&h[q2], 1u);
        atomicAdd(&h[q3], 1u);
    }
    __syncthreads();

    // ---- phase 2: banded on-the-fly contraction, ALLOCATION-FREE ----
    // Pass A sums the band kernel; pass B recomputes exp and accumulates.
    // Live state ~6 scalars -> no spill. exp is recomputed (VALU was 5%).
    {
        const int lane = t & 63;
        const int wv   = t >> 6;
        #pragma unroll
        for (int k = 0; k < 4; ++k) {
            const int   q  = 16 * lane + 4 * wv + k;
            const float n  = (float)h[q];
            const float cq = ((float)q + 0.5f) * (1.0f / (float)NQ);
            const int   jc = (int)(cq * 63.0f + 0.5f);       // nearest bin
            int js = jc - 7;
            js = js < 0 ? 0 : (js > NBINS - BANDW ? NBINS - BANDW : js);
            float s = 1e-12f;
            #pragma unroll
            for (int i = 0; i < BANDW; ++i) {
                const float d = (cq - cl[js + i]) * 50.0f;   // (x-c)/sigma
                s += __expf(-0.5f * d * d);
            }
            const float scale = n / s;                        // n * per-pixel norm
            #pragma unroll
            for (int i = 0; i < BANDW; ++i) {
                const float d = (cq - cl[js + i]) * 50.0f;
                atomicAdd(&fh[js + i], __expf(-0.5f * d * d) * scale);
            }
        }
    }
    __syncthreads();

    // ---- phase 3: handoff to disjoint slot (contention-free RMW writes) ----
    if (t < NBINS) {
        const float old = atomicExch(&g_part[bid * NBINS + t], fh[t]);
        asm volatile("" :: "v"(old));     // keep RMW live across the barrier
    }
    __syncthreads();   // s_waitcnt vmcnt(0) before s_barrier: exchanges ack'd

    if (t == 0)
        s_last = ((atomicAdd(&g_ticket[img * 32], 1u) & 31u) == 31u) ? 1u : 0u;
    __syncthreads();
    if (!s_last) return;

    // ---- last block of this image: coherent reads (disjoint addresses,
    //      two independent accumulator chains so the RMWs pipeline).
    {
        const int j = t & 63;             // bin
        const int g = t >> 6;             // quarter: parts g*8 .. g*8+7
        float* base = (float*)&g_part[(size_t)(img * BPI + g * 8) * NBINS + j];
        float s0 = 0.0f, s1 = 0.0f;
        #pragma unroll
        for (int b = 0; b < 8; b += 2) {
            s0 += atomicAdd(&base[(b + 0) * NBINS], 0.0f);
            s1 += atomicAdd(&base[(b + 1) * NBINS], 0.0f);
        }
        red[g][j] = s0 + s1;
    }
    __syncthreads();

    if (t < NBINS) {
        const float hsum = red[0][t] + red[1][t] + red[2][t] + red[3][t];
        const float hm   = hsum * (1.0f / (float)IMG_PIX);    // mean over pixels
        float ss = hm;
        #pragma unroll
        for (int off = 32; off > 0; off >>= 1) ss += __shfl_xor(ss, off, 64);
        out[img * NBINS + t] = hm / (ss + 1e-12f);            // per-image normalize
    }
}

extern "C" void kernel_launch(void* const* d_in, const int* in_sizes, int n_in,
                              void* d_out, int out_size, void* d_ws, size_t ws_size,
                              hipStream_t stream)
{
    const float* x       = (const float*)d_in[0];   // (8,3,512,512) fp32
    const float* centers = (const float*)d_in[1];   // (64,) fp32
    float* out           = (float*)d_out;           // (8,3,64) fp32
    (void)d_ws; (void)ws_size;

    soft_hist_fused<<<CNT_BLOCKS, 256, 0, stream>>>(x, centers, out);
}

// Round 9
// 74.038 us; speedup vs baseline: 1.8759x; 1.8759x over previous
//
#include <hip/hip_runtime.h>

// Soft histogram via quantization table:
//   hist[b,c,j] = (1/P) * sum_pixels f_j(x),  f_j(x) = k_j(x)/(sum_j k_j(x)+1e-12)
// f depends only on x -> quantize x into NQ cells, precompute f at cell centers,
// reduce to integer histogram + tiny contraction. absmax 1.2e-4 vs 3.3e-4 tol.
//
// R2:  two dispatches, disjoint partials.                     90.0 us
// R3/4: 1024-thread finalize -> container died twice. Banned.
// R5:  wide-unroll 256-thr finalize.                          75.7 us
// R6:  8-way split + __threadfence (L2 maintenance x192).     86.9 us
// R7:  fence-free atomic split.                               74.0 us  <- best
// R8-R10: fused single-dispatch: 78 us kernel, invariant under handoff-
//      contention (R9) and register (R10) changes. Diagnosis: float
//      atomicAdd lowers to a CAS LOOP without unsafe-fp-atomics; the fused
//      phase-2 did 16K LDS float-CAS per block (serialized, counter-
//      invisible). Also established: replay overhead ~17.5 us is per-GRAPH,
//      not per-dispatch -> fusion has no headroom. Fusion abandoned.
// R11: R7 verbatim, except K2's float atomics use unsafeAtomicAdd
//      (HW global_atomic_add_f32): slice-accumulate (12.3K adds, 8-deep
//      contention -> CAS retries gone) + finalizer coherent reads (+0.0f).

#define NQ      1024
#define NBINS   64
#define NIMG    24            // B*C = 8*3
#define IMG_PIX (512 * 512)   // 262144 pixels per (b,c) image
#define BPI     32            // count blocks per image
#define CNT_BLOCKS (NIMG * BPI)        // 768
#define TBL_BLOCKS (NQ / 4)            // 256 (4 quant cells per 256-thread block)
#define SLICES  8                      // finalize blocks per image
#define SLICE_Q (NQ / SLICES)          // 128 q-cells per finalize block

// ---- K1: fused count (blocks 0..767) + table build (blocks 768..1023) ----
__global__ __launch_bounds__(256) void soft_hist_k1(
    const float* __restrict__ x, const float* __restrict__ centers,
    float* __restrict__ table, unsigned int* __restrict__ parts,
    float* __restrict__ hist_acc, unsigned int* __restrict__ tickets)
{
    const int bid = blockIdx.x;
    const int t   = threadIdx.x;

    if (bid < CNT_BLOCKS) {
        // ---- per-(image,slice) histogram over NQ quant cells ----
        __shared__ unsigned int h[NQ];
        #pragma unroll
        for (int k = 0; k < NQ / 256; ++k) h[t + k * 256] = 0u;
        __syncthreads();

        // Block covers 2048 float4 (8192 pixels), contiguous 32 KB chunk.
        const float4* x4 = (const float4*)x + (size_t)bid * (IMG_PIX / 4 / BPI);

        // Prefetch all 8 float4 into registers -> 8 HBM loads in flight.
        float4 v[8];
        #pragma unroll
        for (int r = 0; r < 8; ++r) v[r] = x4[r * 256 + t];

        #pragma unroll
        for (int r = 0; r < 8; ++r) {
            const float4 p = v[r];
            int q0 = (int)(p.x * (float)NQ); q0 = q0 < 0 ? 0 : (q0 > NQ - 1 ? NQ - 1 : q0);
            int q1 = (int)(p.y * (float)NQ); q1 = q1 < 0 ? 0 : (q1 > NQ - 1 ? NQ - 1 : q1);
            int q2 = (int)(p.z * (float)NQ); q2 = q2 < 0 ? 0 : (q2 > NQ - 1 ? NQ - 1 : q2);
            int q3 = (int)(p.w * (float)NQ); q3 = q3 < 0 ? 0 : (q3 > NQ - 1 ? NQ - 1 : q3);
            atomicAdd(&h[q0], 1u);   // u32 atomics: native HW op, not CAS
            atomicAdd(&h[q1], 1u);
            atomicAdd(&h[q2], 1u);
            atomicAdd(&h[q3], 1u);
        }
        __syncthreads();

        // Plain coalesced store of this block's partial histogram (disjoint slot).
        unsigned int* dst = parts + (size_t)bid * NQ;
        #pragma unroll
        for (int k = 0; k < NQ / 256; ++k) dst[t + k * 256] = h[t + k * 256];
    } else {
        // First table block zero-inits the accumulator + tickets (ws is
        // poisoned each replay; K1->K2 stream order makes zeros visible).
        if (bid == CNT_BLOCKS) {
            #pragma unroll
            for (int k = 0; k < (NIMG * NBINS) / 256; ++k)
                hist_acc[t + k * 256] = 0.0f;
            if (t < NIMG) tickets[t] = 0u;
        }

        // ---- table[q][j] = normalized Gaussian kernel at quant-cell center q ----
        const int lane = t & 63;                       // bin (64 bins == 1 wave)
        const int q    = (bid - CNT_BLOCKS) * 4 + (t >> 6);
        const float cq = ((float)q + 0.5f) * (1.0f / (float)NQ);
        // (x - c)/(SIGMA + 1e-12); 0.02 + 1e-12 rounds to 0.02f in fp32
        const float d  = (cq - centers[lane]) * 50.0f;
        const float e  = expf(-0.5f * d * d);
        float s = e;
        #pragma unroll
        for (int off = 32; off > 0; off >>= 1) s += __shfl_xor(s, off, 64);
        table[q * NBINS + lane] = e / (s + 1e-12f);
    }
}

// ---- K2: 8 blocks per image; each contracts a 128-q slice and atomically
//      accumulates (HW fp atomics); last block per image (ticket) normalizes.
__global__ __launch_bounds__(256) void soft_hist_final(
    const unsigned int* __restrict__ parts, const float* __restrict__ table,
    float* hist_acc, unsigned int* tickets, float* __restrict__ out)
{
    __shared__ float sh[2 * SLICE_Q];
    __shared__ float tf[SLICE_Q];
    __shared__ float part[4][NBINS];
    __shared__ unsigned int is_last;

    const int t   = threadIdx.x;
    const int img = blockIdx.x / SLICES;
    const int k   = blockIdx.x % SLICES;       // q-slice index

    // Phase 1: tf[c] = sum over 32 partials of cell q = k*128 + c.
    // Thread t: cell c = t&127, partial-half h = t>>7 -> 16 loads in flight.
    {
        const int c = t & (SLICE_Q - 1);
        const int h = t >> 7;
        const unsigned int* src = parts + (size_t)img * BPI * NQ
                                 + (size_t)(h * 16) * NQ + (k * SLICE_Q + c);
        unsigned int s = 0;
        #pragma unroll
        for (int b = 0; b < 16; ++b) s += src[(size_t)b * NQ];
        sh[h * SLICE_Q + c] = (float)s;
    }
    __syncthreads();
    if (t < SLICE_Q) tf[t] = sh[t] + sh[SLICE_Q + t];
    __syncthreads();

    // Phase 2: contraction over this slice. Group g (of 4) covers 32 q's;
    // lane j = bin. 32 fully-unrolled coalesced 256B table reads in flight.
    const int j = t & 63;
    const int g = t >> 6;
    float acc = 0.0f;
    const float* tb = table + (size_t)(k * SLICE_Q + g * 32) * NBINS + j;
    #pragma unroll
    for (int qq = 0; qq < 32; ++qq)
        acc += tb[(size_t)qq * NBINS] * tf[g * 32 + qq];   // tf read is wave-broadcast
    part[g][j] = acc;
    __syncthreads();

    // Accumulate this slice's 64-float partial: HW global_atomic_add_f32
    // (unsafeAtomicAdd), NOT the default CAS loop. Keep the return live so
    // the vmcnt(0) before the next barrier covers the RMW completion.
    if (t < NBINS) {
        const float old = unsafeAtomicAdd(&hist_acc[img * NBINS + t],
                                          part[0][t] + part[1][t] + part[2][t] + part[3][t]);
        asm volatile("" :: "v"(old));
    }
    __syncthreads();   // compiler emits s_waitcnt vmcnt(0) before s_barrier

    if (t == 0)
        is_last = (atomicAdd(&tickets[img], 1u) == SLICES - 1) ? 1u : 0u;
    __syncthreads();
    if (!is_last) return;

    // Last block of this image: coherent read via HW atomic RMW (+0.0f),
    // then normalize. All 8 slices' adds are complete (their barriers
    // drained vmcnt before their tickets).
    if (t < NBINS) {
        const float hsum = unsafeAtomicAdd(&hist_acc[img * NBINS + t], 0.0f);
        const float hm   = hsum * (1.0f / (float)IMG_PIX);   // mean over pixels
        float ss = hm;
        #pragma unroll
        for (int off = 32; off > 0; off >>= 1) ss += __shfl_xor(ss, off, 64);
        out[img * NBINS + t] = hm / (ss + 1e-12f);           // per-image normalize
    }
}

extern "C" void kernel_launch(void* const* d_in, const int* in_sizes, int n_in,
                              void* d_out, int out_size, void* d_ws, size_t ws_size,
                              hipStream_t stream)
{
    const float* x       = (const float*)d_in[0];   // (8,3,512,512) fp32
    const float* centers = (const float*)d_in[1];   // (64,) fp32
    float* out           = (float*)d_out;           // (8,3,64) fp32

    char* ws = (char*)d_ws;
    float*        table    = (float*)ws;                   // 256 KB
    ws += (size_t)NQ * NBINS * sizeof(float);
    unsigned int* parts    = (unsigned int*)ws;            // 3 MB
    ws += (size_t)CNT_BLOCKS * NQ * sizeof(unsigned int);
    float*        hist_acc = (float*)ws;                   // 6 KB
    ws += (size_t)NIMG * NBINS * sizeof(float);
    unsigned int* tickets  = (unsigned int*)ws;            // 96 B

    soft_hist_k1<<<CNT_BLOCKS + TBL_BLOCKS, 256, 0, stream>>>(
        x, centers, table, parts, hist_acc, tickets);
    soft_hist_final<<<NIMG * SLICES, 256, 0, stream>>>(
        parts, table, hist_acc, tickets, out);
}